// Round 6
// baseline (26.524 us; speedup 1.0000x reference)
//
#include <hip/hip_runtime.h>
#include <math.h>

#define NLAB 2000
#define BATCH 1024
#define LAMBDA_SMOOTH 0.1f

#define RPG 8            // batch rows per group
#define NRG 128          // row groups (1024/8)
#define ES  8            // edge slices
#define NB  (NRG * ES)   // fused-kernel grid = 1024 blocks (4/CU by 36 KB LDS)
#define IMG_U16 18000    // padded image: (2000 + 2000/8)*8 u16 = 36000 B
#define IMG_V4  2250

// u16 slot of (label l, row 0): 8 u16 per label + one 16B pad granule per 8 labels.
__device__ __forceinline__ int slotOf(int l) { return (l + (l >> 3)) << 3; }

__device__ __forceinline__ ushort f2bf(float f) {   // round-to-nearest-even bf16
    unsigned u = __float_as_uint(f);
    return (ushort)((u + 0x7fffu + ((u >> 16) & 1u)) >> 16);
}
__device__ __forceinline__ float bf_lo(unsigned u) { return __uint_as_float(u << 16); }
__device__ __forceinline__ float bf_hi(unsigned u) { return __uint_as_float(u & 0xffff0000u); }

// ---------------------------------------------------------------------------
// Fused kernel: each block (rg, es) converts its OWN 8-row image from
// logits/labels (128 KB fp32, L2-shared by the 8 same-rg blocks on one XCD),
// packs it transposed+padded into LDS, then runs its edge slice.
//   map: x = bid&7 (XCD), j = bid>>3, rg = x*16 + (j&15), es = j>>4
// No yPack intermediate, no K1 launch, d_ws = partials only.
// ---------------------------------------------------------------------------
__global__ __launch_bounds__(256) void fused_edge_kernel(
        const float* __restrict__ logits, const float* __restrict__ labels,
        const float* __restrict__ ew, const int* __restrict__ li,
        const int* __restrict__ ri, int nEdges, float* __restrict__ partials) {
    __shared__ uint4 shv[IMG_V4];               // 36000 B
    __shared__ float red[4];
    const int x   = blockIdx.x & 7;             // XCD slot
    const int j   = blockIdx.x >> 3;
    const int rg  = x * 16 + (j & 15);
    const int es  = j >> 4;
    const int tid = threadIdx.x;
    ushort* sh = (ushort*)shv;

    // ---- Phase 1: convert + transpose into LDS ----
    // Thread owns labels l = tid, tid+256, ... ; packs 8 rows into one uint4
    // and writes with a single 16B-aligned ds_write_b128.
    for (int l = tid; l < NLAB; l += 256) {
        unsigned p[4];
#pragma unroll
        for (int h = 0; h < 4; ++h) {
            float y2[2];
#pragma unroll
            for (int q = 0; q < 2; ++q) {
                const int r   = 2 * h + q;
                const int idx = (rg * RPG + r) * NLAB + l;   // coalesced in l
                const float lg  = logits[idx];
                const float lab = labels[idx];
                const float sg  = 1.0f / (1.0f + __expf(-lg));
                const bool ann  = (lab == 0.0f) || (lab == 1.0f);
                y2[q] = ann ? (2.0f * lab - 1.0f) : (2.0f * sg - 1.0f);
            }
            p[h] = (unsigned)f2bf(y2[0]) | ((unsigned)f2bf(y2[1]) << 16);
        }
        uint4 v; v.x = p[0]; v.y = p[1]; v.z = p[2]; v.w = p[3];
        *(uint4*)(sh + slotOf(l)) = v;
    }
    __syncthreads();

    // ---- Phase 2: edge slice reduction ----
    const int per = (nEdges + ES - 1) / ES;
    const int e0  = es * per;
    int e1 = e0 + per; if (e1 > nEdges) e1 = nEdges;

    float acc = 0.0f;
#pragma unroll 4
    for (int e = e0 + tid; e < e1; e += 256) {
        const int   l = li[e];
        const int   r = ri[e];
        const float w = ew[e];
        const uint4 A = *(const uint4*)(sh + slotOf(l));   // 8 rows, left col
        const uint4 B = *(const uint4*)(sh + slotOf(r));   // 8 rows, right col
        float s = 0.0f;
        float d;
        d = bf_lo(A.x) - bf_lo(B.x); s = fmaf(d, d, s);
        d = bf_hi(A.x) - bf_hi(B.x); s = fmaf(d, d, s);
        d = bf_lo(A.y) - bf_lo(B.y); s = fmaf(d, d, s);
        d = bf_hi(A.y) - bf_hi(B.y); s = fmaf(d, d, s);
        d = bf_lo(A.z) - bf_lo(B.z); s = fmaf(d, d, s);
        d = bf_hi(A.z) - bf_hi(B.z); s = fmaf(d, d, s);
        d = bf_lo(A.w) - bf_lo(B.w); s = fmaf(d, d, s);
        d = bf_hi(A.w) - bf_hi(B.w); s = fmaf(d, d, s);
        acc = fmaf(w, s, acc);
    }

#pragma unroll
    for (int off = 32; off > 0; off >>= 1)
        acc += __shfl_down(acc, off, 64);
    if ((tid & 63) == 0) red[tid >> 6] = acc;
    __syncthreads();
    if (tid == 0)
        partials[blockIdx.x] = red[0] + red[1] + red[2] + red[3];
}

// ---------------------------------------------------------------------------
// K3: sum partials, scale. Single block, fixed order -> deterministic.
// ---------------------------------------------------------------------------
__global__ __launch_bounds__(1024) void final_reduce_kernel(
        const float* __restrict__ partials, int n, float scale,
        float* __restrict__ out) {
    float s = 0.0f;
    for (int i = threadIdx.x; i < n; i += blockDim.x) s += partials[i];
#pragma unroll
    for (int off = 32; off > 0; off >>= 1)
        s += __shfl_down(s, off, 64);

    __shared__ float smem[16];
    const int wave = threadIdx.x >> 6;
    const int lane = threadIdx.x & 63;
    if (lane == 0) smem[wave] = s;
    __syncthreads();
    if (threadIdx.x == 0) {
        float t = 0.0f;
        for (int i = 0; i < (int)(blockDim.x >> 6); ++i) t += smem[i];
        out[0] = scale * t;
    }
}

// ---------------------------------------------------------------------------
extern "C" void kernel_launch(void* const* d_in, const int* in_sizes, int n_in,
                              void* d_out, int out_size, void* d_ws, size_t ws_size,
                              hipStream_t stream) {
    const float* logits = (const float*)d_in[0];
    const float* labels = (const float*)d_in[1];
    const float* ew     = (const float*)d_in[2];
    const int*   li     = (const int*)d_in[3];
    const int*   ri     = (const int*)d_in[4];
    float* out          = (float*)d_out;

    const int nEdges = in_sizes[2];

    float* partials = (float*)d_ws;             // NB floats (4 KB)

    fused_edge_kernel<<<NB, 256, 0, stream>>>(logits, labels, ew, li, ri,
                                              nEdges, partials);

    const float scale = LAMBDA_SMOOTH / ((float)BATCH * (float)nEdges);
    final_reduce_kernel<<<1, 1024, 0, stream>>>(partials, NB, scale, out);
}

// Round 7
// 25.416 us; speedup vs baseline: 1.0436x; 1.0436x over previous
//
#include <hip/hip_runtime.h>
#include <math.h>

#define NLAB 2000
#define BATCH 1024
#define LAMBDA_SMOOTH 0.1f

#define RPG 8            // batch rows per group
#define NRG 128          // row groups (1024/8)
#define K1_SL 8          // label slices per row group in K1
#define K1_LPS 250       // labels per slice
#define ES 8             // edge slices in K2
#define NB2 1024         // K2 grid = 128 rg x 8 es
#define IMG_U16 18000    // padded image: (2000 + 2000/8)*8 u16 = 36000 B
#define IMG_V4  2250     // same in uint4

// u16 slot of (label l, row 0): 8 u16 per label + one 16B pad granule per 8 labels.
__device__ __forceinline__ int slotOf(int l) { return (l + (l >> 3)) << 3; }

__device__ __forceinline__ ushort f2bf(float f) {   // round-to-nearest-even bf16
    unsigned u = __float_as_uint(f);
    return (ushort)((u + 0x7fffu + ((u >> 16) & 1u)) >> 16);
}
__device__ __forceinline__ float bf_lo(unsigned u) { return __uint_as_float(u << 16); }
__device__ __forceinline__ float bf_hi(unsigned u) { return __uint_as_float(u & 0xffff0000u); }

__device__ __forceinline__ float edge_term(const ushort* sh, int l, int r) {
    const uint4 A = *(const uint4*)(sh + slotOf(l));
    const uint4 B = *(const uint4*)(sh + slotOf(r));
    float s = 0.0f, d;
    d = bf_lo(A.x) - bf_lo(B.x); s = fmaf(d, d, s);
    d = bf_hi(A.x) - bf_hi(B.x); s = fmaf(d, d, s);
    d = bf_lo(A.y) - bf_lo(B.y); s = fmaf(d, d, s);
    d = bf_hi(A.y) - bf_hi(B.y); s = fmaf(d, d, s);
    d = bf_lo(A.z) - bf_lo(B.z); s = fmaf(d, d, s);
    d = bf_hi(A.z) - bf_hi(B.z); s = fmaf(d, d, s);
    d = bf_lo(A.w) - bf_lo(B.w); s = fmaf(d, d, s);
    d = bf_hi(A.w) - bf_hi(B.w); s = fmaf(d, d, s);
    return s;
}

// ---------------------------------------------------------------------------
// K1: convert + pack-transpose (unchanged from R5). grid 1024.
// ---------------------------------------------------------------------------
__global__ __launch_bounds__(256) void convert_pack_kernel(
        const float* __restrict__ logits, const float* __restrict__ labels,
        uint4* __restrict__ yPack) {
    __shared__ ushort sh[2304];                 // max slice span = 2256 u16
    const int rg  = blockIdx.x >> 3;
    const int s   = blockIdx.x & 7;
    const int tid = threadIdx.x;

    const int l0 = s * K1_LPS;
    const int u0 = slotOf(l0);                  // 16B-aligned u16 start
    const int u1 = slotOf(l0 + K1_LPS);
    if (tid < K1_LPS) {
        const int l  = l0 + tid;
        const int us = slotOf(l) - u0;
#pragma unroll
        for (int r = 0; r < RPG; ++r) {
            const int idx = (rg * RPG + r) * NLAB + l;   // coalesced in tid
            const float lg  = logits[idx];
            const float lab = labels[idx];
            const float sg  = 1.0f / (1.0f + __expf(-lg));
            const bool ann  = (lab == 0.0f) || (lab == 1.0f);
            const float y   = ann ? (2.0f * lab - 1.0f) : (2.0f * sg - 1.0f);
            sh[us + r] = f2bf(y);
        }
    }
    __syncthreads();
    const int nV4 = (u1 - u0) >> 3;
    const uint4* shv = (const uint4*)sh;
    uint4* dst = yPack + (size_t)rg * IMG_V4 + (u0 >> 3);
    for (int i = tid; i < nV4; i += 256) dst[i] = shv[i];
}

// ---------------------------------------------------------------------------
// K2: edge reduction. XCD-local image sharing (map unchanged from R5).
// NEW: contiguous per-thread edge runs + int4/float4 index loads.
//   per-slice size padded to 1024 -> every thread's 4-edge chunk is
//   16B-aligned; lanes' int4 loads form contiguous 1KB coalesced segments.
//   8 ds_read_b128 per chunk in flight; sorted left_idx makes a thread's
//   left-slot reads mostly repeat (LDS broadcast).
// ---------------------------------------------------------------------------
__global__ __launch_bounds__(256) void edge_reduce_kernel(
        const uint4* __restrict__ yPack, const float* __restrict__ ew,
        const int* __restrict__ li, const int* __restrict__ ri,
        int nEdges, float* __restrict__ partials) {
    __shared__ uint4 shv[IMG_V4];               // 36000 B
    __shared__ float red[4];
    const int x   = blockIdx.x & 7;             // XCD slot
    const int j   = blockIdx.x >> 3;
    const int rg  = x * 16 + (j & 15);
    const int es  = j >> 4;
    const int tid = threadIdx.x;

    const uint4* src = yPack + (size_t)rg * IMG_V4;
    for (int i = tid; i < IMG_V4; i += 256) shv[i] = src[i];
    __syncthreads();
    const ushort* sh = (const ushort*)shv;

    // per-slice edge count, padded to 1024 (=256 threads * 4) for alignment
    const int per = (((nEdges + ES - 1) / ES) + 1023) & ~1023;
    const int ept = per >> 8;                   // edges per thread (mult of 4)
    const int e0  = es * per;
    const int e1  = min(e0 + per, nEdges);

    const int base = e0 + tid * ept;
    const int end  = min(base + ept, e1);

    float acc = 0.0f;
    int e = base;
    for (; e + 4 <= end; e += 4) {              // aligned vector chunks
        const int4   L = *(const int4*)(li + e);
        const int4   R = *(const int4*)(ri + e);
        const float4 W = *(const float4*)(ew + e);
        acc = fmaf(W.x, edge_term(sh, L.x, R.x), acc);
        acc = fmaf(W.y, edge_term(sh, L.y, R.y), acc);
        acc = fmaf(W.z, edge_term(sh, L.z, R.z), acc);
        acc = fmaf(W.w, edge_term(sh, L.w, R.w), acc);
    }
    for (; e < end; ++e)                        // scalar tail (boundary thread)
        acc = fmaf(ew[e], edge_term(sh, li[e], ri[e]), acc);

#pragma unroll
    for (int off = 32; off > 0; off >>= 1)
        acc += __shfl_down(acc, off, 64);
    if ((tid & 63) == 0) red[tid >> 6] = acc;
    __syncthreads();
    if (tid == 0)
        partials[blockIdx.x] = red[0] + red[1] + red[2] + red[3];
}

// ---------------------------------------------------------------------------
// K3: sum partials, scale. Single block, fixed order -> deterministic.
// ---------------------------------------------------------------------------
__global__ __launch_bounds__(1024) void final_reduce_kernel(
        const float* __restrict__ partials, int n, float scale,
        float* __restrict__ out) {
    float s = 0.0f;
    for (int i = threadIdx.x; i < n; i += blockDim.x) s += partials[i];
#pragma unroll
    for (int off = 32; off > 0; off >>= 1)
        s += __shfl_down(s, off, 64);

    __shared__ float smem[16];
    const int wave = threadIdx.x >> 6;
    const int lane = threadIdx.x & 63;
    if (lane == 0) smem[wave] = s;
    __syncthreads();
    if (threadIdx.x == 0) {
        float t = 0.0f;
        for (int i = 0; i < (int)(blockDim.x >> 6); ++i) t += smem[i];
        out[0] = scale * t;
    }
}

// ---------------------------------------------------------------------------
extern "C" void kernel_launch(void* const* d_in, const int* in_sizes, int n_in,
                              void* d_out, int out_size, void* d_ws, size_t ws_size,
                              hipStream_t stream) {
    const float* logits = (const float*)d_in[0];
    const float* labels = (const float*)d_in[1];
    const float* ew     = (const float*)d_in[2];
    const int*   li     = (const int*)d_in[3];
    const int*   ri     = (const int*)d_in[4];
    float* out          = (float*)d_out;

    const int nEdges = in_sizes[2];

    // workspace: yPack images (128 * 36000 B), partials (4 KB)
    uint4* yPack    = (uint4*)d_ws;
    float* partials = (float*)((char*)d_ws + (size_t)NRG * IMG_U16 * sizeof(ushort));

    convert_pack_kernel<<<NRG * K1_SL, 256, 0, stream>>>(logits, labels, yPack);

    edge_reduce_kernel<<<NB2, 256, 0, stream>>>(yPack, ew, li, ri, nEdges, partials);

    const float scale = LAMBDA_SMOOTH / ((float)BATCH * (float)nEdges);
    final_reduce_kernel<<<1, 1024, 0, stream>>>(partials, NB2, scale, out);
}

// Round 8
// 19.950 us; speedup vs baseline: 1.3295x; 1.2740x over previous
//
#include <hip/hip_runtime.h>
#include <math.h>

#define NLAB 2000
#define BATCH 1024
#define LAMBDA_SMOOTH 0.1f

#define RPG 8            // batch rows per group
#define NRG 128          // row groups (1024/8)
#define K1_SL 8          // label slices per row group in K1
#define K1_LPS 250       // labels per slice
#define ES 8             // edge slices in K2
#define NB2 1024         // K2 grid = 128 rg x 8 es
#define IMG_U16 18000    // padded image: (2000 + 2000/8)*8 u16 = 36000 B
#define IMG_V4  2250     // same in uint4

// u16 slot of (label l, row 0): 8 u16 per label + one 16B pad granule per 8 labels.
__device__ __forceinline__ int slotOf(int l) { return (l + (l >> 3)) << 3; }

__device__ __forceinline__ ushort f2bf(float f) {   // round-to-nearest-even bf16
    unsigned u = __float_as_uint(f);
    return (ushort)((u + 0x7fffu + ((u >> 16) & 1u)) >> 16);
}
__device__ __forceinline__ float bf_lo(unsigned u) { return __uint_as_float(u << 16); }
__device__ __forceinline__ float bf_hi(unsigned u) { return __uint_as_float(u & 0xffff0000u); }

// ---------------------------------------------------------------------------
// K1: convert + pack-transpose (unchanged from R5). grid 1024, 256 thr.
// ---------------------------------------------------------------------------
__global__ __launch_bounds__(256) void convert_pack_kernel(
        const float* __restrict__ logits, const float* __restrict__ labels,
        uint4* __restrict__ yPack) {
    __shared__ ushort sh[2304];                 // max slice span = 2256 u16
    const int rg  = blockIdx.x >> 3;
    const int s   = blockIdx.x & 7;
    const int tid = threadIdx.x;

    const int l0 = s * K1_LPS;
    const int u0 = slotOf(l0);                  // 16B-aligned u16 start
    const int u1 = slotOf(l0 + K1_LPS);
    if (tid < K1_LPS) {
        const int l  = l0 + tid;
        const int us = slotOf(l) - u0;
#pragma unroll
        for (int r = 0; r < RPG; ++r) {
            const int idx = (rg * RPG + r) * NLAB + l;   // coalesced in tid
            const float lg  = logits[idx];
            const float lab = labels[idx];
            const float sg  = 1.0f / (1.0f + __expf(-lg));
            const bool ann  = (lab == 0.0f) || (lab == 1.0f);
            const float y   = ann ? (2.0f * lab - 1.0f) : (2.0f * sg - 1.0f);
            sh[us + r] = f2bf(y);
        }
    }
    __syncthreads();
    const int nV4 = (u1 - u0) >> 3;
    const uint4* shv = (const uint4*)sh;
    uint4* dst = yPack + (size_t)rg * IMG_V4 + (u0 >> 3);
    for (int i = tid; i < nV4; i += 256) dst[i] = shv[i];
}

// ---------------------------------------------------------------------------
// K2: edge reduction. Loop layout = R5 (strided; wave covers 64 consecutive
// edges -> left-column LDS reads are near-broadcast thanks to sorted li).
// CHANGE vs R5: 512-thread blocks (8 waves) with same 36 KB LDS
//   -> still 4 blocks/CU (144 KB LDS, 2048 thr) but 32 waves/CU (100% occ)
//   -> double the latency hiding for the LDS-gather dependency chains.
// XCD map unchanged: x = bid&7, j = bid>>3, rg = x*16 + (j&15), es = j>>4.
// ---------------------------------------------------------------------------
__global__ __launch_bounds__(512) void edge_reduce_kernel(
        const uint4* __restrict__ yPack, const float* __restrict__ ew,
        const int* __restrict__ li, const int* __restrict__ ri,
        int nEdges, float* __restrict__ partials) {
    __shared__ uint4 shv[IMG_V4];               // 36000 B
    __shared__ float red[8];
    const int x   = blockIdx.x & 7;             // XCD slot
    const int j   = blockIdx.x >> 3;
    const int rg  = x * 16 + (j & 15);
    const int es  = j >> 4;
    const int tid = threadIdx.x;

    const uint4* src = yPack + (size_t)rg * IMG_V4;
    for (int i = tid; i < IMG_V4; i += 512) shv[i] = src[i];
    __syncthreads();
    const ushort* sh = (const ushort*)shv;

    const int per = (nEdges + ES - 1) / ES;
    const int e0  = es * per;
    int e1 = e0 + per; if (e1 > nEdges) e1 = nEdges;

    float acc = 0.0f;
#pragma unroll 2
    for (int e = e0 + tid; e < e1; e += 512) {
        const int   l = li[e];
        const int   r = ri[e];
        const float w = ew[e];
        const uint4 A = *(const uint4*)(sh + slotOf(l));   // 8 rows, left col
        const uint4 B = *(const uint4*)(sh + slotOf(r));   // 8 rows, right col
        float s = 0.0f;
        float d;
        d = bf_lo(A.x) - bf_lo(B.x); s = fmaf(d, d, s);
        d = bf_hi(A.x) - bf_hi(B.x); s = fmaf(d, d, s);
        d = bf_lo(A.y) - bf_lo(B.y); s = fmaf(d, d, s);
        d = bf_hi(A.y) - bf_hi(B.y); s = fmaf(d, d, s);
        d = bf_lo(A.z) - bf_lo(B.z); s = fmaf(d, d, s);
        d = bf_hi(A.z) - bf_hi(B.z); s = fmaf(d, d, s);
        d = bf_lo(A.w) - bf_lo(B.w); s = fmaf(d, d, s);
        d = bf_hi(A.w) - bf_hi(B.w); s = fmaf(d, d, s);
        acc = fmaf(w, s, acc);
    }

#pragma unroll
    for (int off = 32; off > 0; off >>= 1)
        acc += __shfl_down(acc, off, 64);
    if ((tid & 63) == 0) red[tid >> 6] = acc;
    __syncthreads();
    if (tid == 0) {
        float t = 0.0f;
#pragma unroll
        for (int i = 0; i < 8; ++i) t += red[i];
        partials[blockIdx.x] = t;
    }
}

// ---------------------------------------------------------------------------
// K3: sum partials, scale. Single block, fixed order -> deterministic.
// ---------------------------------------------------------------------------
__global__ __launch_bounds__(1024) void final_reduce_kernel(
        const float* __restrict__ partials, int n, float scale,
        float* __restrict__ out) {
    float s = 0.0f;
    for (int i = threadIdx.x; i < n; i += blockDim.x) s += partials[i];
#pragma unroll
    for (int off = 32; off > 0; off >>= 1)
        s += __shfl_down(s, off, 64);

    __shared__ float smem[16];
    const int wave = threadIdx.x >> 6;
    const int lane = threadIdx.x & 63;
    if (lane == 0) smem[wave] = s;
    __syncthreads();
    if (threadIdx.x == 0) {
        float t = 0.0f;
        for (int i = 0; i < (int)(blockDim.x >> 6); ++i) t += smem[i];
        out[0] = scale * t;
    }
}

// ---------------------------------------------------------------------------
extern "C" void kernel_launch(void* const* d_in, const int* in_sizes, int n_in,
                              void* d_out, int out_size, void* d_ws, size_t ws_size,
                              hipStream_t stream) {
    const float* logits = (const float*)d_in[0];
    const float* labels = (const float*)d_in[1];
    const float* ew     = (const float*)d_in[2];
    const int*   li     = (const int*)d_in[3];
    const int*   ri     = (const int*)d_in[4];
    float* out          = (float*)d_out;

    const int nEdges = in_sizes[2];

    // workspace: yPack images (128 * 36000 B), partials (4 KB)
    uint4* yPack    = (uint4*)d_ws;
    float* partials = (float*)((char*)d_ws + (size_t)NRG * IMG_U16 * sizeof(ushort));

    convert_pack_kernel<<<NRG * K1_SL, 256, 0, stream>>>(logits, labels, yPack);

    edge_reduce_kernel<<<NB2, 512, 0, stream>>>(yPack, ew, li, ri, nEdges, partials);

    const float scale = LAMBDA_SMOOTH / ((float)BATCH * (float)nEdges);
    final_reduce_kernel<<<1, 1024, 0, stream>>>(partials, NB2, scale, out);
}

// Round 9
// 19.474 us; speedup vs baseline: 1.3620x; 1.0244x over previous
//
#include <hip/hip_runtime.h>
#include <math.h>

#define NLAB 2000
#define BATCH 1024
#define LAMBDA_SMOOTH 0.1f

#define RPG 16           // batch rows per group
#define NRG 64           // row groups (1024/16)
#define ES 8             // edge slices in K2
#define NB2 512          // K2 grid = 64 rg x 8 es  (2 blocks/CU, 100% occ)
#define IMG_U16 32496    // 2000*16 + 62 pad-granules * 8 u16 = 64992 B
#define IMG_V4  4062     // same in uint4 (64992/16)

// u16 slot of (label l, row 0): 16 u16 per label + one 16B pad granule per
// 32 labels -> gather start positions cover 8 distinct bank-quads.
__device__ __forceinline__ int slot16(int l) { return (l << 4) + ((l >> 5) << 3); }

__device__ __forceinline__ ushort f2bf(float f) {   // round-to-nearest-even bf16
    unsigned u = __float_as_uint(f);
    return (ushort)((u + 0x7fffu + ((u >> 16) & 1u)) >> 16);
}
__device__ __forceinline__ float bf_lo(unsigned u) { return __uint_as_float(u << 16); }
__device__ __forceinline__ float bf_hi(unsigned u) { return __uint_as_float(u & 0xffff0000u); }

__device__ __forceinline__ float pair_term(unsigned a, unsigned b) {
    const float d0 = bf_lo(a) - bf_lo(b);
    const float d1 = bf_hi(a) - bf_hi(b);
    return fmaf(d0, d0, d1 * d1);
}

// ---------------------------------------------------------------------------
// K1: convert + pack. grid 512: rg = bid>>3, slice = bid&7 (250 labels).
// Thread owns one label: 32 row-loads (coalesced in l), packs 16 rows into
// 2 uint4, writes directly to yPack (lanes' 32B blocks ~contiguous).
// ---------------------------------------------------------------------------
__global__ __launch_bounds__(256) void convert_pack_kernel(
        const float* __restrict__ logits, const float* __restrict__ labels,
        ushort* __restrict__ yPack) {
    const int rg = blockIdx.x >> 3;
    const int s  = blockIdx.x & 7;
    const int t  = threadIdx.x;
    if (t >= 250) return;
    const int l = s * 250 + t;

    unsigned p[8];
#pragma unroll
    for (int h = 0; h < 8; ++h) {
        float y2[2];
#pragma unroll
        for (int q = 0; q < 2; ++q) {
            const int r   = 2 * h + q;
            const int idx = (rg * RPG + r) * NLAB + l;   // coalesced in t
            const float lg  = logits[idx];
            const float lab = labels[idx];
            const float sg  = 1.0f / (1.0f + __expf(-lg));
            const bool ann  = (lab == 0.0f) || (lab == 1.0f);
            const float y   = ann ? (2.0f * lab - 1.0f) : (2.0f * sg - 1.0f);
            y2[q] = y;
        }
        p[h] = (unsigned)f2bf(y2[0]) | ((unsigned)f2bf(y2[1]) << 16);
    }
    ushort* dst = yPack + (size_t)rg * IMG_U16 + slot16(l);
    uint4 v0; v0.x = p[0]; v0.y = p[1]; v0.z = p[2]; v0.w = p[3];
    uint4 v1; v1.x = p[4]; v1.y = p[5]; v1.z = p[6]; v1.w = p[7];
    *(uint4*)(dst)     = v0;    // rows 0-7
    *(uint4*)(dst + 8) = v1;    // rows 8-15
}

// ---------------------------------------------------------------------------
// K2: edge reduction. 1024 threads, 64992 B LDS -> 2 blocks/CU, 32 waves/CU.
// XCD map: x = bid&7 (XCD), j = bid>>3, rg = x*8 + (j&7), es = j>>3
//   -> the 8 es-blocks of one rg share an XCD; image L2-resident after 1st.
// Strided edge loop (wave = 64 consecutive edges -> left col ~broadcast).
// 1-deep software pipeline on index loads; OOB lanes clamped with w=0.
// ---------------------------------------------------------------------------
__global__ __launch_bounds__(1024, 8) void edge_reduce_kernel(
        const ushort* __restrict__ yPack, const float* __restrict__ ew,
        const int* __restrict__ li, const int* __restrict__ ri,
        int nEdges, float* __restrict__ partials) {
    __shared__ uint4 shv[IMG_V4];               // 64992 B
    __shared__ float red[16];
    const int x   = blockIdx.x & 7;             // XCD slot
    const int j   = blockIdx.x >> 3;
    const int rg  = x * 8 + (j & 7);
    const int es  = j >> 3;
    const int tid = threadIdx.x;

    const uint4* src = (const uint4*)(yPack + (size_t)rg * IMG_U16);
    for (int i = tid; i < IMG_V4; i += 1024) shv[i] = src[i];
    __syncthreads();
    const ushort* sh = (const ushort*)shv;

    const int per = (nEdges + ES - 1) / ES;
    const int e0  = es * per;
    const int e1  = min(e0 + per, nEdges);      // >= 1 for es=0; may be < e0
    const int niter = (per + 1023) >> 10;

    int e  = e0 + tid;
    int ec = min(e, e1 - 1); if (ec < 0) ec = 0;
    int   l = li[ec];
    int   r = ri[ec];
    float w = (e < e1) ? ew[ec] : 0.0f;

    float acc = 0.0f;
    for (int k = 0; k < niter; ++k) {
        // prefetch next iteration's indices (uniform condition, no divergence)
        const int en  = e + 1024;
        int ln = l, rn = r; float wn = 0.0f;
        if (k + 1 < niter) {
            int ecn = min(en, e1 - 1); if (ecn < 0) ecn = 0;
            ln = li[ecn];
            rn = ri[ecn];
            wn = (en < e1) ? ew[ecn] : 0.0f;
        }
        // compute current edge: 16 rows via 4x ds_read_b128
        const int sl = slot16(l);
        const int sr = slot16(r);
        const uint4 A0 = *(const uint4*)(sh + sl);
        const uint4 A1 = *(const uint4*)(sh + sl + 8);
        const uint4 B0 = *(const uint4*)(sh + sr);
        const uint4 B1 = *(const uint4*)(sh + sr + 8);
        float s = 0.0f;
        s += pair_term(A0.x, B0.x);
        s += pair_term(A0.y, B0.y);
        s += pair_term(A0.z, B0.z);
        s += pair_term(A0.w, B0.w);
        s += pair_term(A1.x, B1.x);
        s += pair_term(A1.y, B1.y);
        s += pair_term(A1.z, B1.z);
        s += pair_term(A1.w, B1.w);
        acc = fmaf(w, s, acc);

        e = en; l = ln; r = rn; w = wn;
    }

#pragma unroll
    for (int off = 32; off > 0; off >>= 1)
        acc += __shfl_down(acc, off, 64);
    if ((tid & 63) == 0) red[tid >> 6] = acc;
    __syncthreads();
    if (tid == 0) {
        float t = 0.0f;
#pragma unroll
        for (int i = 0; i < 16; ++i) t += red[i];
        partials[blockIdx.x] = t;
    }
}

// ---------------------------------------------------------------------------
// K3: sum partials, scale. Single block, fixed order -> deterministic.
// ---------------------------------------------------------------------------
__global__ __launch_bounds__(1024) void final_reduce_kernel(
        const float* __restrict__ partials, int n, float scale,
        float* __restrict__ out) {
    float s = 0.0f;
    for (int i = threadIdx.x; i < n; i += blockDim.x) s += partials[i];
#pragma unroll
    for (int off = 32; off > 0; off >>= 1)
        s += __shfl_down(s, off, 64);

    __shared__ float smem[16];
    const int wave = threadIdx.x >> 6;
    const int lane = threadIdx.x & 63;
    if (lane == 0) smem[wave] = s;
    __syncthreads();
    if (threadIdx.x == 0) {
        float t = 0.0f;
        for (int i = 0; i < (int)(blockDim.x >> 6); ++i) t += smem[i];
        out[0] = scale * t;
    }
}

// ---------------------------------------------------------------------------
extern "C" void kernel_launch(void* const* d_in, const int* in_sizes, int n_in,
                              void* d_out, int out_size, void* d_ws, size_t ws_size,
                              hipStream_t stream) {
    const float* logits = (const float*)d_in[0];
    const float* labels = (const float*)d_in[1];
    const float* ew     = (const float*)d_in[2];
    const int*   li     = (const int*)d_in[3];
    const int*   ri     = (const int*)d_in[4];
    float* out          = (float*)d_out;

    const int nEdges = in_sizes[2];

    // workspace: yPack images (64 * 64992 B = 4.16 MB), partials (2 KB)
    ushort* yPack    = (ushort*)d_ws;
    float*  partials = (float*)((char*)d_ws + (size_t)NRG * IMG_U16 * sizeof(ushort));

    convert_pack_kernel<<<NRG * 8, 256, 0, stream>>>(logits, labels, yPack);

    edge_reduce_kernel<<<NB2, 1024, 0, stream>>>(yPack, ew, li, ri, nEdges, partials);

    const float scale = LAMBDA_SMOOTH / ((float)BATCH * (float)nEdges);
    final_reduce_kernel<<<1, 1024, 0, stream>>>(partials, NB2, scale, out);
}

// Round 10
// 18.241 us; speedup vs baseline: 1.4541x; 1.0676x over previous
//
#include <hip/hip_runtime.h>
#include <math.h>

#define NLAB 2000
#define BATCH 1024
#define LAMBDA_SMOOTH 0.1f

#define RPG 16           // batch rows per group
#define NRG 64           // row groups (1024/16)
#define ES 8             // edge slices in K2
#define NB2 512          // K2 grid = 64 rg x 8 es  (2 blocks/CU, 100% occ)
#define IMG_U16 32496    // 2000*16 + 62 pad-granules * 8 u16 = 64992 B
#define IMG_V4  4062     // same in uint4 (64992/16)

typedef _Float16 h2 __attribute__((ext_vector_type(2)));

// u16 slot of (label l, row 0): 16 u16 per label + one 16B pad granule per
// 32 labels -> gather start positions cover 8 distinct bank-quads.
__device__ __forceinline__ int slot16(int l) { return (l << 4) + ((l >> 5) << 3); }

// one packed sub + one v_dot2_f32_f16: accumulates (a-b).(a-b) for 2 rows
__device__ __forceinline__ float dot_acc(unsigned ua, unsigned ub, float acc) {
    const h2 a = __builtin_bit_cast(h2, ua);
    const h2 b = __builtin_bit_cast(h2, ub);
    const h2 d = a - b;
    return __builtin_amdgcn_fdot2(d, d, acc, false);
}

// ---------------------------------------------------------------------------
// K1: convert + pack (f16). grid 512: rg = bid>>3, slice = bid&7 (250 labels).
// Thread owns one label: 32 row-loads (coalesced in l), packs 16 rows into
// 2 uint4 of f16 pairs, writes directly to yPack.
// ---------------------------------------------------------------------------
__global__ __launch_bounds__(256) void convert_pack_kernel(
        const float* __restrict__ logits, const float* __restrict__ labels,
        ushort* __restrict__ yPack) {
    const int rg = blockIdx.x >> 3;
    const int s  = blockIdx.x & 7;
    const int t  = threadIdx.x;
    if (t >= 250) return;
    const int l = s * 250 + t;

    unsigned p[8];
#pragma unroll
    for (int h = 0; h < 8; ++h) {
        float y2[2];
#pragma unroll
        for (int q = 0; q < 2; ++q) {
            const int r   = 2 * h + q;
            const int idx = (rg * RPG + r) * NLAB + l;   // coalesced in t
            const float lg  = logits[idx];
            const float lab = labels[idx];
            const float sg  = 1.0f / (1.0f + __expf(-lg));
            const bool ann  = (lab == 0.0f) || (lab == 1.0f);
            y2[q] = ann ? (2.0f * lab - 1.0f) : (2.0f * sg - 1.0f);
        }
        h2 hv;
        hv.x = (_Float16)y2[0];
        hv.y = (_Float16)y2[1];
        p[h] = __builtin_bit_cast(unsigned, hv);
    }
    ushort* dst = yPack + (size_t)rg * IMG_U16 + slot16(l);
    uint4 v0; v0.x = p[0]; v0.y = p[1]; v0.z = p[2]; v0.w = p[3];
    uint4 v1; v1.x = p[4]; v1.y = p[5]; v1.z = p[6]; v1.w = p[7];
    *(uint4*)(dst)     = v0;    // rows 0-7
    *(uint4*)(dst + 8) = v1;    // rows 8-15
}

// ---------------------------------------------------------------------------
// K2: edge reduction. 1024 threads, 64992 B LDS -> 2 blocks/CU, 32 waves/CU.
// XCD map: x = bid&7 (XCD), j = bid>>3, rg = x*8 + (j&7), es = j>>3.
// Strided edge loop (wave = 64 consecutive edges -> left col ~broadcast).
// Software pipeline: indices fetched 2 iters ahead, LDS data 1 iter ahead,
// compute on current -> both L2 index latency and LDS latency hidden.
// ---------------------------------------------------------------------------
__global__ __launch_bounds__(1024, 8) void edge_reduce_kernel(
        const ushort* __restrict__ yPack, const float* __restrict__ ew,
        const int* __restrict__ li, const int* __restrict__ ri,
        int nEdges, float* __restrict__ partials) {
    __shared__ uint4 shv[IMG_V4];               // 64992 B
    __shared__ float red[16];
    const int x   = blockIdx.x & 7;             // XCD slot
    const int j   = blockIdx.x >> 3;
    const int rg  = x * 8 + (j & 7);
    const int es  = j >> 3;
    const int tid = threadIdx.x;

    const uint4* src = (const uint4*)(yPack + (size_t)rg * IMG_U16);
    for (int i = tid; i < IMG_V4; i += 1024) shv[i] = src[i];
    __syncthreads();
    const ushort* sh = (const ushort*)shv;

    const int per   = (nEdges + ES - 1) / ES;
    const int e0    = es * per;
    const int e1    = min(e0 + per, nEdges);
    const int niter = (per + 1023) >> 10;       // uniform across all blocks

    // ---- pipeline prologue ----
    int e = e0 + tid;
    // stage 0 indices (current)
    int   ec = min(e, e1 - 1); if (ec < 0) ec = 0;
    int   l  = li[ec],  r  = ri[ec];
    float w  = (e < e1) ? ew[ec] : 0.0f;
    // stage 0 data
    int sl = slot16(l), sr = slot16(r);
    uint4 A0 = *(const uint4*)(sh + sl);
    uint4 A1 = *(const uint4*)(sh + sl + 8);
    uint4 B0 = *(const uint4*)(sh + sr);
    uint4 B1 = *(const uint4*)(sh + sr + 8);
    // stage 1 indices (next)
    int   l1 = l, r1 = r; float w1 = 0.0f;
    if (niter > 1) {
        const int en = e + 1024;
        int ecn = min(en, e1 - 1); if (ecn < 0) ecn = 0;
        l1 = li[ecn]; r1 = ri[ecn];
        w1 = (en < e1) ? ew[ecn] : 0.0f;
    }

    float acc = 0.0f;
    for (int k = 0; k < niter; ++k) {
        // fetch indices for k+2 (uniform branch)
        int l2 = l1, r2 = r1; float w2 = 0.0f;
        if (k + 2 < niter) {
            const int en2 = e + 2048;
            int ec2 = min(en2, e1 - 1); if (ec2 < 0) ec2 = 0;
            l2 = li[ec2]; r2 = ri[ec2];
            w2 = (en2 < e1) ? ew[ec2] : 0.0f;
        }
        // issue LDS reads for k+1 (indices ready from last iter)
        const int sln = slot16(l1), srn = slot16(r1);
        const uint4 An0 = *(const uint4*)(sh + sln);
        const uint4 An1 = *(const uint4*)(sh + sln + 8);
        const uint4 Bn0 = *(const uint4*)(sh + srn);
        const uint4 Bn1 = *(const uint4*)(sh + srn + 8);

        // compute current edge: 16 rows = 8 packed dot2s
        float s = 0.0f;
        s = dot_acc(A0.x, B0.x, s);
        s = dot_acc(A0.y, B0.y, s);
        s = dot_acc(A0.z, B0.z, s);
        s = dot_acc(A0.w, B0.w, s);
        s = dot_acc(A1.x, B1.x, s);
        s = dot_acc(A1.y, B1.y, s);
        s = dot_acc(A1.z, B1.z, s);
        s = dot_acc(A1.w, B1.w, s);
        acc = fmaf(w, s, acc);

        // rotate pipeline
        e += 1024;
        w = w1; w1 = w2;
        l1 = l2; r1 = r2;
        A0 = An0; A1 = An1; B0 = Bn0; B1 = Bn1;
    }

#pragma unroll
    for (int off = 32; off > 0; off >>= 1)
        acc += __shfl_down(acc, off, 64);
    if ((tid & 63) == 0) red[tid >> 6] = acc;
    __syncthreads();
    if (tid == 0) {
        float t = 0.0f;
#pragma unroll
        for (int i = 0; i < 16; ++i) t += red[i];
        partials[blockIdx.x] = t;
    }
}

// ---------------------------------------------------------------------------
// K3: sum partials, scale. Single block, fixed order -> deterministic.
// ---------------------------------------------------------------------------
__global__ __launch_bounds__(512) void final_reduce_kernel(
        const float* __restrict__ partials, int n, float scale,
        float* __restrict__ out) {
    float s = 0.0f;
    for (int i = threadIdx.x; i < n; i += blockDim.x) s += partials[i];
#pragma unroll
    for (int off = 32; off > 0; off >>= 1)
        s += __shfl_down(s, off, 64);

    __shared__ float smem[8];
    const int wave = threadIdx.x >> 6;
    const int lane = threadIdx.x & 63;
    if (lane == 0) smem[wave] = s;
    __syncthreads();
    if (threadIdx.x == 0) {
        float t = 0.0f;
        for (int i = 0; i < (int)(blockDim.x >> 6); ++i) t += smem[i];
        out[0] = scale * t;
    }
}

// ---------------------------------------------------------------------------
extern "C" void kernel_launch(void* const* d_in, const int* in_sizes, int n_in,
                              void* d_out, int out_size, void* d_ws, size_t ws_size,
                              hipStream_t stream) {
    const float* logits = (const float*)d_in[0];
    const float* labels = (const float*)d_in[1];
    const float* ew     = (const float*)d_in[2];
    const int*   li     = (const int*)d_in[3];
    const int*   ri     = (const int*)d_in[4];
    float* out          = (float*)d_out;

    const int nEdges = in_sizes[2];

    // workspace: yPack images (64 * 64992 B = 4.16 MB), partials (2 KB)
    ushort* yPack    = (ushort*)d_ws;
    float*  partials = (float*)((char*)d_ws + (size_t)NRG * IMG_U16 * sizeof(ushort));

    convert_pack_kernel<<<NRG * 8, 256, 0, stream>>>(logits, labels, yPack);

    edge_reduce_kernel<<<NB2, 1024, 0, stream>>>(yPack, ew, li, ri, nEdges, partials);

    const float scale = LAMBDA_SMOOTH / ((float)BATCH * (float)nEdges);
    final_reduce_kernel<<<1, 512, 0, stream>>>(partials, NB2, scale, out);
}